// Round 6
// baseline (317.794 us; speedup 1.0000x reference)
//
#include <hip/hip_runtime.h>
#include <hip/hip_bf16.h>

typedef __attribute__((ext_vector_type(8))) short short8;
typedef __attribute__((ext_vector_type(4))) float f32x4;

__device__ __forceinline__ unsigned short f2bf(float f) {
  union { float f; unsigned u; } v; v.f = f;
  unsigned r = v.u + 0x7FFFu + ((v.u >> 16) & 1u);
  return (unsigned short)(r >> 16);
}
__device__ __forceinline__ float bf2f(unsigned short h) {
  union { unsigned u; float f; } v; v.u = ((unsigned)h) << 16;
  return v.f;
}
__device__ __forceinline__ unsigned pkbf(float a, float b) {
  __hip_bfloat162 h = __float22bfloat162_rn(float2{a, b});
  union { __hip_bfloat162 h; unsigned u; } cv; cv.h = h;
  return cv.u;
}

// ---------------- prep: cast x -> bf16 (z=0) + transpose+cast 4 weights (z=1..4) ----------------
__global__ void prep(const float* __restrict__ x, const float* __restrict__ wq,
                     const float* __restrict__ wk, const float* __restrict__ wv,
                     const float* __restrict__ wo, unsigned short* __restrict__ xb,
                     unsigned short* __restrict__ wt, unsigned short* __restrict__ wot) {
  const int z = blockIdx.z, tid = threadIdx.x;
  if (z == 0) {
    int id = blockIdx.y * 64 + blockIdx.x;  // 0..4095
#pragma unroll
    for (int rep = 0; rep < 2; ++rep) {
      int i = (rep * 4096 + id) * 256 + tid;  // 2M float4 total
      float4 v = ((const float4*)x)[i];
      ushort4 o;
      o.x = f2bf(v.x); o.y = f2bf(v.y); o.z = f2bf(v.z); o.w = f2bf(v.w);
      ((ushort4*)xb)[i] = o;
    }
    return;
  }
  __shared__ float tile[32][33];
  const float* src;
  unsigned short* dst;
  int N;
  if (z == 1) { src = wq; dst = wt; N = 2048; }
  else if (z == 2) { src = wk; dst = wt + 2048ull * 2048; N = 512; }
  else if (z == 3) { src = wv; dst = wt + 2560ull * 2048; N = 512; }
  else { src = wo; dst = wot; N = 2048; }
  const int K = 2048;
  int n0 = blockIdx.x * 32, k0 = blockIdx.y * 32;
  if (n0 >= N) return;
  int xx = tid & 31, yy = tid >> 5;  // 32 x 8
#pragma unroll
  for (int j = 0; j < 4; ++j) tile[yy + 8 * j][xx] = src[(size_t)(k0 + yy + 8 * j) * N + n0 + xx];
  __syncthreads();
#pragma unroll
  for (int j = 0; j < 4; ++j) dst[(size_t)(n0 + yy + 8 * j) * K + k0 + xx] = f2bf(tile[xx][yy + 8 * j]);
}

// ---------------- GEMM BK=64, swizzled LDS: C(MxN) = A(MxK) * Bt(NxK)^T ----------------
// MODE 0: fp32 C. MODE 1 (QKV): cols<2048 bf16 Q; 2048..2559 K with fused RoPE (fp32-accurate);
// >=2560 V packed-b64 transposed into vt[b][kvh][d][s].
template <int MODE>
__global__ __launch_bounds__(256, 2) void gemm_bt64(const unsigned short* __restrict__ A,
                                                    const unsigned short* __restrict__ Bt,
                                                    void* __restrict__ Cv, int K, int ldc,
                                                    unsigned short* __restrict__ vt,
                                                    const float* __restrict__ fcos,
                                                    const float* __restrict__ fsin) {
  __shared__ alignas(16) unsigned short As[128 * 64];
  __shared__ alignas(16) unsigned short Bs[128 * 64];
  const int t = threadIdx.x;
  const int lane = t & 63, w = t >> 6;
  const int l15 = lane & 15, quad = lane >> 4;
  const int bn0 = blockIdx.x * 128, bm0 = blockIdx.y * 128;
  const int wm = (w >> 1) * 64, wn = (w & 1) * 64;
  const unsigned short* Ab = A + (size_t)bm0 * K;
  const unsigned short* Bb = Bt + (size_t)bn0 * K;
  const int asw = l15 & 7;

  f32x4 acc[4][4];
  const f32x4 zf = {0.f, 0.f, 0.f, 0.f};
#pragma unroll
  for (int i = 0; i < 4; ++i)
#pragma unroll
    for (int j = 0; j < 4; ++j) acc[i][j] = zf;

  for (int k0 = 0; k0 < K; k0 += 64) {
    __syncthreads();
#pragma unroll
    for (int r = 0; r < 4; ++r) {
      int e = r * 256 + t;
      int row = e >> 3, cslot = e & 7;
      int cg = cslot ^ (row & 7);
      const unsigned short* ga = Ab + (size_t)row * K + k0 + cg * 8;
      __builtin_amdgcn_global_load_lds((const __attribute__((address_space(1))) void*)ga,
                                       (__attribute__((address_space(3))) void*)(As + e * 8), 16, 0, 0);
      const unsigned short* gb = Bb + (size_t)row * K + k0 + cg * 8;
      __builtin_amdgcn_global_load_lds((const __attribute__((address_space(1))) void*)gb,
                                       (__attribute__((address_space(3))) void*)(Bs + e * 8), 16, 0, 0);
    }
    __syncthreads();
#pragma unroll
    for (int s = 0; s < 2; ++s) {
      short8 af[4], bf[4];
#pragma unroll
      for (int i = 0; i < 4; ++i)
        af[i] = *reinterpret_cast<const short8*>(As + (wm + i * 16 + l15) * 64 + (((s * 4 + quad) ^ asw) * 8));
#pragma unroll
      for (int j = 0; j < 4; ++j)
        bf[j] = *reinterpret_cast<const short8*>(Bs + (wn + j * 16 + l15) * 64 + (((s * 4 + quad) ^ asw) * 8));
#pragma unroll
      for (int i = 0; i < 4; ++i)
#pragma unroll
        for (int j = 0; j < 4; ++j)
          acc[i][j] = __builtin_amdgcn_mfma_f32_16x16x32_bf16(af[i], bf[j], acc[i][j], 0, 0, 0);
    }
  }

  if (MODE == 1 && bn0 >= 2560) {
    // V block -> vt[b][kvh][d][s], packed 4 rows per b64
    const int b = bm0 >> 11;
#pragma unroll
    for (int i = 0; i < 4; ++i) {
      int srow = (bm0 + wm + i * 16 + quad * 4) & 2047;
#pragma unroll
      for (int j = 0; j < 4; ++j) {
        int vcol = bn0 - 2560 + wn + j * 16 + l15;
        int kvh = vcol >> 6, d = vcol & 63;
        uint2 pk = make_uint2(pkbf(acc[i][j][0], acc[i][j][1]), pkbf(acc[i][j][2], acc[i][j][3]));
        *reinterpret_cast<uint2*>(vt + ((size_t)(b * 8 + kvh) * 64 + d) * 2048 + srow) = pk;
      }
    }
  } else if (MODE == 1 && bn0 >= 2048) {
    // K block: fused RoPE (pairs = adjacent lanes), fp32-accurate, then bf16 store
#pragma unroll
    for (int i = 0; i < 4; ++i) {
      int row = bm0 + wm + i * 16 + quad * 4;
      int s0 = row & 2047;
#pragma unroll
      for (int j = 0; j < 4; ++j) {
        int col = bn0 + wn + j * 16 + l15;
        int f = (col & 63) >> 1;
        float sign = (col & 1) ? 1.f : -1.f;
#pragma unroll
        for (int r = 0; r < 4; ++r) {
          float v = acc[i][j][r];
          float partner = __shfl_xor(v, 1, 64);
          float c = fcos[(size_t)(s0 + r) * 32 + f];
          float sn = fsin[(size_t)(s0 + r) * 32 + f];
          ((unsigned short*)Cv)[(size_t)(row + r) * ldc + col] = f2bf(v * c + sign * partner * sn);
        }
      }
    }
  } else {
#pragma unroll
    for (int i = 0; i < 4; ++i)
#pragma unroll
      for (int j = 0; j < 4; ++j)
#pragma unroll
        for (int r = 0; r < 4; ++r) {
          size_t row = (size_t)(bm0 + wm + i * 16 + quad * 4 + r);
          size_t col = (size_t)(bn0 + wn + j * 16 + l15);
          if (MODE == 1)
            ((unsigned short*)Cv)[row * ldc + col] = f2bf(acc[i][j][r]);
          else
            ((float*)Cv)[row * ldc + col] = acc[i][j][r];
        }
  }
}

// ---------------- flash attention: 256 q-rows/block, 4 waves x 64 rows, dynamic work queue ----
// Items 512 = qb(8, longest first) x h(32) x b(2). Counter at cnt (d_out[0], memset to 0).
__global__ __launch_bounds__(256, 2) void flash_attn(const unsigned short* __restrict__ qkv,
                                                     const unsigned short* __restrict__ vt,
                                                     const float* __restrict__ fcos,
                                                     const float* __restrict__ fsin,
                                                     unsigned short* __restrict__ out,
                                                     int* __restrict__ cnt) {
  __shared__ alignas(16) unsigned short Ks[64 * 64];
  __shared__ alignas(16) unsigned short Vs[64 * 64];
  __shared__ alignas(16) unsigned short Ps[256 * 64];
  __shared__ float Ls[256];
  __shared__ int s_item;
  const int t = threadIdx.x, lane = t & 63, w = t >> 6;
  const int l15 = lane & 15, quad = lane >> 4;
  const int srow = t >> 3, sc8 = t & 7;
  const int soff = srow * 64 + ((sc8 ^ (srow & 7)) * 8);
  const int asw = l15 & 7;
  const float SC = 0.18033688011112042f;  // (1/8)*log2(e), folded into Q
  const f32x4 zf = {0.f, 0.f, 0.f, 0.f};

  while (true) {
    __syncthreads();
    if (t == 0) s_item = atomicAdd(cnt, 1);
    __syncthreads();
    const int item = s_item;
    if (item >= 512) break;
    const int qb = 7 - (item >> 6);
    const int rest = item & 63;
    const int h = rest & 31, b = rest >> 5;
    const int q0 = qb * 256;
    const int kvh = h >> 2;
    const size_t rowB = (size_t)b * 2048;
    const unsigned short* Qg = qkv + (rowB + q0) * 2560 + h * 64;
    const unsigned short* Kg = qkv + rowB * 2560 + 2048 + kvh * 64;
    const unsigned short* Vtg = vt + (size_t)(b * 8 + kvh) * 64 * 2048;

    // Q fragments: fused RoPE + folded softmax scale
    short8 qf[4][2];
#pragma unroll
    for (int mt = 0; mt < 4; ++mt)
#pragma unroll
      for (int s = 0; s < 2; ++s) {
        int qrow = w * 64 + mt * 16 + l15;
        short8 raw = *reinterpret_cast<const short8*>(Qg + (size_t)qrow * 2560 + s * 32 + quad * 8);
        f32x4 c4 = *reinterpret_cast<const f32x4*>(fcos + (size_t)(q0 + qrow) * 32 + s * 16 + quad * 4);
        f32x4 s4 = *reinterpret_cast<const f32x4*>(fsin + (size_t)(q0 + qrow) * 32 + s * 16 + quad * 4);
        short8 o;
#pragma unroll
        for (int k = 0; k < 4; ++k) {
          float xr = bf2f((unsigned short)raw[2 * k]);
          float xi = bf2f((unsigned short)raw[2 * k + 1]);
          o[2 * k] = (short)f2bf((xr * c4[k] - xi * s4[k]) * SC);
          o[2 * k + 1] = (short)f2bf((xr * s4[k] + xi * c4[k]) * SC);
        }
        qf[mt][s] = o;
      }

    f32x4 oacc[4][4];
#pragma unroll
    for (int mt = 0; mt < 4; ++mt)
#pragma unroll
      for (int nt = 0; nt < 4; ++nt) oacc[mt][nt] = zf;
    float lsum[4] = {0.f, 0.f, 0.f, 0.f};

    const int kb_end = 4 * (qb + 1);
    const int qmaxw = q0 + w * 64 + 63;
    short8 kreg[2], vreg[2];
#pragma unroll
    for (int r = 0; r < 2; ++r) {
      kreg[r] = *reinterpret_cast<const short8*>(Kg + (size_t)(srow + 32 * r) * 2560 + sc8 * 8);
      vreg[r] = *reinterpret_cast<const short8*>(Vtg + (size_t)(srow + 32 * r) * 2048 + sc8 * 8);
    }

    for (int kb = 0; kb < kb_end; ++kb) {
      __syncthreads();
#pragma unroll
      for (int r = 0; r < 2; ++r) {
        *reinterpret_cast<short8*>(Ks + soff + r * 32 * 64) = kreg[r];
        *reinterpret_cast<short8*>(Vs + soff + r * 32 * 64) = vreg[r];
      }
      __syncthreads();
      if (kb + 1 < kb_end) {
#pragma unroll
        for (int r = 0; r < 2; ++r) {
          kreg[r] = *reinterpret_cast<const short8*>(Kg + (size_t)((kb + 1) * 64 + srow + 32 * r) * 2560 + sc8 * 8);
          vreg[r] = *reinterpret_cast<const short8*>(Vtg + (size_t)(srow + 32 * r) * 2048 + (kb + 1) * 64 + sc8 * 8);
        }
      }
      if (kb * 64 > qmaxw) continue;  // wave fully masked
      const bool needMask = (kb * 64 + 63) > (q0 + w * 64);

#pragma unroll
      for (int kvt = 0; kvt < 4; ++kvt) {
        // skip if this kvt's covering PV half is dead for this wave
        if (needMask && (kb * 64 + (kvt >> 1) * 32 > qmaxw)) continue;
        const int pcol = ((kvt * 2 + (quad >> 1)) ^ asw) * 8 + (quad & 1) * 4;
        if (needMask && (kb * 64 + kvt * 16 > qmaxw)) {
          // fully-masked kvt inside a live half: zero Ps, skip compute
#pragma unroll
          for (int mt = 0; mt < 4; ++mt)
            *reinterpret_cast<uint2*>(Ps + (size_t)(w * 64 + mt * 16 + l15) * 64 + pcol) = make_uint2(0u, 0u);
          continue;
        }
        f32x4 st[4];
#pragma unroll
        for (int mt = 0; mt < 4; ++mt) st[mt] = zf;
#pragma unroll
        for (int s = 0; s < 2; ++s) {
          short8 kf = *reinterpret_cast<const short8*>(Ks + (kvt * 16 + l15) * 64 + ((s * 4 + quad) ^ asw) * 8);
#pragma unroll
          for (int mt = 0; mt < 4; ++mt)
            st[mt] = __builtin_amdgcn_mfma_f32_16x16x32_bf16(kf, qf[mt][s], st[mt], 0, 0, 0);
        }
        if (needMask) {
          const int kvb = kb * 64 + kvt * 16 + quad * 4;
#pragma unroll
          for (int mt = 0; mt < 4; ++mt) {
            const int qg = q0 + w * 64 + mt * 16 + l15;
            float p[4];
#pragma unroll
            for (int r = 0; r < 4; ++r) {
              float pv = __builtin_amdgcn_exp2f(st[mt][r]);
              p[r] = (kvb + r > qg) ? 0.f : pv;
            }
            lsum[mt] += (p[0] + p[1]) + (p[2] + p[3]);
            *reinterpret_cast<uint2*>(Ps + (size_t)(w * 64 + mt * 16 + l15) * 64 + pcol) =
                make_uint2(pkbf(p[0], p[1]), pkbf(p[2], p[3]));
          }
        } else {
#pragma unroll
          for (int mt = 0; mt < 4; ++mt) {
            float p[4];
#pragma unroll
            for (int r = 0; r < 4; ++r) p[r] = __builtin_amdgcn_exp2f(st[mt][r]);
            lsum[mt] += (p[0] + p[1]) + (p[2] + p[3]);
            *reinterpret_cast<uint2*>(Ps + (size_t)(w * 64 + mt * 16 + l15) * 64 + pcol) =
                make_uint2(pkbf(p[0], p[1]), pkbf(p[2], p[3]));
          }
        }
      }

      // O += P V
#pragma unroll
      for (int s = 0; s < 2; ++s) {
        if (needMask && (kb * 64 + s * 32 > qmaxw)) continue;  // dead half
        short8 vf[4];
#pragma unroll
        for (int nt = 0; nt < 4; ++nt)
          vf[nt] = *reinterpret_cast<const short8*>(Vs + (nt * 16 + l15) * 64 + ((s * 4 + quad) ^ asw) * 8);
#pragma unroll
        for (int mt = 0; mt < 4; ++mt) {
          short8 pf = *reinterpret_cast<const short8*>(Ps + (size_t)(w * 64 + mt * 16 + l15) * 64 + ((s * 4 + quad) ^ asw) * 8);
#pragma unroll
          for (int nt = 0; nt < 4; ++nt)
            oacc[mt][nt] = __builtin_amdgcn_mfma_f32_16x16x32_bf16(pf, vf[nt], oacc[mt][nt], 0, 0, 0);
        }
      }
    }

    // epilogue: reduce l over quads, broadcast via LDS, scale & store
#pragma unroll
    for (int mt = 0; mt < 4; ++mt) {
      lsum[mt] += __shfl_xor(lsum[mt], 16, 64);
      lsum[mt] += __shfl_xor(lsum[mt], 32, 64);
    }
    if (quad == 0) {
#pragma unroll
      for (int mt = 0; mt < 4; ++mt) Ls[w * 64 + mt * 16 + l15] = lsum[mt];
    }
    float linv[4][4];
#pragma unroll
    for (int mt = 0; mt < 4; ++mt)
#pragma unroll
      for (int r = 0; r < 4; ++r) linv[mt][r] = 1.f / Ls[w * 64 + mt * 16 + quad * 4 + r];

#pragma unroll
    for (int mt = 0; mt < 4; ++mt)
#pragma unroll
      for (int nt = 0; nt < 4; ++nt)
#pragma unroll
        for (int r = 0; r < 4; ++r) {
          size_t row = rowB + (size_t)(q0 + w * 64 + mt * 16 + quad * 4 + r);
          size_t col = (size_t)h * 64 + nt * 16 + l15;
          out[row * 2048 + col] = f2bf(oacc[mt][nt][r] * linv[mt][r]);
        }
  }
}

extern "C" void kernel_launch(void* const* d_in, const int* in_sizes, int n_in, void* d_out,
                              int out_size, void* d_ws, size_t ws_size, hipStream_t stream) {
  const float* x = (const float*)d_in[0];
  const float* fcos = (const float*)d_in[1];
  const float* fsin = (const float*)d_in[2];
  const float* wq = (const float*)d_in[3];
  const float* wk = (const float*)d_in[4];
  const float* wv = (const float*)d_in[5];
  const float* wo = (const float*)d_in[6];

  char* ws = (char*)d_ws;
  unsigned short* xb = (unsigned short*)ws;                       // 4096x2048 bf16  @0      (16 MiB)
  unsigned short* wt = (unsigned short*)(ws + 16777216ull);       // 3072x2048 bf16  @16 MiB (12 MiB)
  unsigned short* wot = (unsigned short*)(ws + 29360128ull);      // 2048x2048 bf16  @28 MiB (8 MiB)
  unsigned short* qkv = (unsigned short*)(ws + 37748736ull);      // 4096x2560 bf16  @36 MiB (20 MiB)
  unsigned short* attno = (unsigned short*)(ws + 58720256ull);    // 4096x2048 bf16  @56 MiB (16 MiB)
  unsigned short* vt = (unsigned short*)(ws + 75497472ull);       // 16x64x2048 bf16 @72 MiB (4 MiB)
  int* cnt = (int*)d_out;  // flash work-queue counter; d_out fully rewritten by final GEMM

  hipMemsetAsync(cnt, 0, 4, stream);
  prep<<<dim3(64, 64, 5), 256, 0, stream>>>(x, wq, wk, wv, wo, xb, wt, wot);
  // QKV GEMM: Q plain, K with fused RoPE, V transposed into vt
  gemm_bt64<1><<<dim3(24, 32), 256, 0, stream>>>(xb, wt, qkv, 2048, 2560, vt, fcos, fsin);
  flash_attn<<<512, 256, 0, stream>>>(qkv, vt, fcos, fsin, attno, cnt);
  gemm_bt64<0><<<dim3(16, 32), 256, 0, stream>>>(attno, wot, d_out, 2048, 2048, nullptr, nullptr, nullptr);
}

// Round 7
// 284.058 us; speedup vs baseline: 1.1188x; 1.1188x over previous
//
#include <hip/hip_runtime.h>
#include <hip/hip_bf16.h>

typedef __attribute__((ext_vector_type(8))) short short8;
typedef __attribute__((ext_vector_type(4))) float f32x4;

__device__ __forceinline__ unsigned short f2bf(float f) {
  union { float f; unsigned u; } v; v.f = f;
  unsigned r = v.u + 0x7FFFu + ((v.u >> 16) & 1u);
  return (unsigned short)(r >> 16);
}
__device__ __forceinline__ float bf2f(unsigned short h) {
  union { unsigned u; float f; } v; v.u = ((unsigned)h) << 16;
  return v.f;
}
__device__ __forceinline__ unsigned pkbf(float a, float b) {
  __hip_bfloat162 h = __float22bfloat162_rn(float2{a, b});
  union { __hip_bfloat162 h; unsigned u; } cv; cv.h = h;
  return cv.u;
}

// ---------------- prep: cast x -> bf16 (z=0) + transpose+cast 4 weights (z=1..4) ----------------
__global__ void prep(const float* __restrict__ x, const float* __restrict__ wq,
                     const float* __restrict__ wk, const float* __restrict__ wv,
                     const float* __restrict__ wo, unsigned short* __restrict__ xb,
                     unsigned short* __restrict__ wt, unsigned short* __restrict__ wot) {
  const int z = blockIdx.z, tid = threadIdx.x;
  if (z == 0) {
    int id = blockIdx.y * 64 + blockIdx.x;  // 0..4095
#pragma unroll
    for (int rep = 0; rep < 2; ++rep) {
      int i = (rep * 4096 + id) * 256 + tid;  // 2M float4 total
      float4 v = ((const float4*)x)[i];
      ushort4 o;
      o.x = f2bf(v.x); o.y = f2bf(v.y); o.z = f2bf(v.z); o.w = f2bf(v.w);
      ((ushort4*)xb)[i] = o;
    }
    return;
  }
  __shared__ float tile[32][33];
  const float* src;
  unsigned short* dst;
  int N;
  if (z == 1) { src = wq; dst = wt; N = 2048; }
  else if (z == 2) { src = wk; dst = wt + 2048ull * 2048; N = 512; }
  else if (z == 3) { src = wv; dst = wt + 2560ull * 2048; N = 512; }
  else { src = wo; dst = wot; N = 2048; }
  const int K = 2048;
  int n0 = blockIdx.x * 32, k0 = blockIdx.y * 32;
  if (n0 >= N) return;
  int xx = tid & 31, yy = tid >> 5;  // 32 x 8
#pragma unroll
  for (int j = 0; j < 4; ++j) tile[yy + 8 * j][xx] = src[(size_t)(k0 + yy + 8 * j) * N + n0 + xx];
  __syncthreads();
#pragma unroll
  for (int j = 0; j < 4; ++j) dst[(size_t)(n0 + yy + 8 * j) * K + k0 + xx] = f2bf(tile[xx][yy + 8 * j]);
}

// ---------------- GEMM BK=64, swizzled LDS: C(MxN) = A(MxK) * Bt(NxK)^T ----------------
// MODE 0: fp32 C. MODE 1 (QKV): cols<2048 bf16 Q; 2048..2559 K with fused RoPE (fp32-accurate);
// >=2560 V packed-b64 transposed into vt[b][kvh][d][s].
template <int MODE>
__global__ __launch_bounds__(256, 2) void gemm_bt64(const unsigned short* __restrict__ A,
                                                    const unsigned short* __restrict__ Bt,
                                                    void* __restrict__ Cv, int K, int ldc,
                                                    unsigned short* __restrict__ vt,
                                                    const float* __restrict__ fcos,
                                                    const float* __restrict__ fsin) {
  __shared__ alignas(16) unsigned short As[128 * 64];
  __shared__ alignas(16) unsigned short Bs[128 * 64];
  const int t = threadIdx.x;
  const int lane = t & 63, w = t >> 6;
  const int l15 = lane & 15, quad = lane >> 4;
  const int bn0 = blockIdx.x * 128, bm0 = blockIdx.y * 128;
  const int wm = (w >> 1) * 64, wn = (w & 1) * 64;
  const unsigned short* Ab = A + (size_t)bm0 * K;
  const unsigned short* Bb = Bt + (size_t)bn0 * K;
  const int asw = l15 & 7;

  f32x4 acc[4][4];
  const f32x4 zf = {0.f, 0.f, 0.f, 0.f};
#pragma unroll
  for (int i = 0; i < 4; ++i)
#pragma unroll
    for (int j = 0; j < 4; ++j) acc[i][j] = zf;

  for (int k0 = 0; k0 < K; k0 += 64) {
    __syncthreads();
#pragma unroll
    for (int r = 0; r < 4; ++r) {
      int e = r * 256 + t;
      int row = e >> 3, cslot = e & 7;
      int cg = cslot ^ (row & 7);
      const unsigned short* ga = Ab + (size_t)row * K + k0 + cg * 8;
      __builtin_amdgcn_global_load_lds((const __attribute__((address_space(1))) void*)ga,
                                       (__attribute__((address_space(3))) void*)(As + e * 8), 16, 0, 0);
      const unsigned short* gb = Bb + (size_t)row * K + k0 + cg * 8;
      __builtin_amdgcn_global_load_lds((const __attribute__((address_space(1))) void*)gb,
                                       (__attribute__((address_space(3))) void*)(Bs + e * 8), 16, 0, 0);
    }
    __syncthreads();
#pragma unroll
    for (int s = 0; s < 2; ++s) {
      short8 af[4], bf[4];
#pragma unroll
      for (int i = 0; i < 4; ++i)
        af[i] = *reinterpret_cast<const short8*>(As + (wm + i * 16 + l15) * 64 + (((s * 4 + quad) ^ asw) * 8));
#pragma unroll
      for (int j = 0; j < 4; ++j)
        bf[j] = *reinterpret_cast<const short8*>(Bs + (wn + j * 16 + l15) * 64 + (((s * 4 + quad) ^ asw) * 8));
#pragma unroll
      for (int i = 0; i < 4; ++i)
#pragma unroll
        for (int j = 0; j < 4; ++j)
          acc[i][j] = __builtin_amdgcn_mfma_f32_16x16x32_bf16(af[i], bf[j], acc[i][j], 0, 0, 0);
    }
  }

  if (MODE == 1 && bn0 >= 2560) {
    // V block -> vt[b][kvh][d][s], packed 4 rows per b64
    const int b = bm0 >> 11;
#pragma unroll
    for (int i = 0; i < 4; ++i) {
      int srow = (bm0 + wm + i * 16 + quad * 4) & 2047;
#pragma unroll
      for (int j = 0; j < 4; ++j) {
        int vcol = bn0 - 2560 + wn + j * 16 + l15;
        int kvh = vcol >> 6, d = vcol & 63;
        uint2 pk = make_uint2(pkbf(acc[i][j][0], acc[i][j][1]), pkbf(acc[i][j][2], acc[i][j][3]));
        *reinterpret_cast<uint2*>(vt + ((size_t)(b * 8 + kvh) * 64 + d) * 2048 + srow) = pk;
      }
    }
  } else if (MODE == 1 && bn0 >= 2048) {
    // K block: fused RoPE (pairs = adjacent lanes), fp32-accurate, then bf16 store
#pragma unroll
    for (int i = 0; i < 4; ++i) {
      int row = bm0 + wm + i * 16 + quad * 4;
      int s0 = row & 2047;
#pragma unroll
      for (int j = 0; j < 4; ++j) {
        int col = bn0 + wn + j * 16 + l15;
        int f = (col & 63) >> 1;
        float sign = (col & 1) ? 1.f : -1.f;
#pragma unroll
        for (int r = 0; r < 4; ++r) {
          float v = acc[i][j][r];
          float partner = __shfl_xor(v, 1, 64);
          float c = fcos[(size_t)(s0 + r) * 32 + f];
          float sn = fsin[(size_t)(s0 + r) * 32 + f];
          ((unsigned short*)Cv)[(size_t)(row + r) * ldc + col] = f2bf(v * c + sign * partner * sn);
        }
      }
    }
  } else {
#pragma unroll
    for (int i = 0; i < 4; ++i)
#pragma unroll
      for (int j = 0; j < 4; ++j)
#pragma unroll
        for (int r = 0; r < 4; ++r) {
          size_t row = (size_t)(bm0 + wm + i * 16 + quad * 4 + r);
          size_t col = (size_t)(bn0 + wn + j * 16 + l15);
          if (MODE == 1)
            ((unsigned short*)Cv)[row * ldc + col] = f2bf(acc[i][j][r]);
          else
            ((float*)Cv)[row * ldc + col] = acc[i][j][r];
        }
  }
}

// ---------------- flash attention: 128 q-rows/block, 4 waves x 32 rows (R5 config) ----------------
__global__ __launch_bounds__(256, 4) void flash_attn(const unsigned short* __restrict__ qkv,
                                                     const unsigned short* __restrict__ vt,
                                                     const float* __restrict__ fcos,
                                                     const float* __restrict__ fsin,
                                                     unsigned short* __restrict__ out) {
  __shared__ alignas(16) unsigned short Ks[64 * 64];
  __shared__ alignas(16) unsigned short Vs[64 * 64];
  __shared__ alignas(16) unsigned short Ps[128 * 64];
  __shared__ float Ls[128];
  const int t = threadIdx.x, lane = t & 63, w = t >> 6;
  const int l15 = lane & 15, quad = lane >> 4;
  const int h = blockIdx.y, b = blockIdx.z;
  // co-resident blocks (idx +256 => h+16) pair qb with 15-qb: every CU gets 68 tile-units
  const int qb = ((int)blockIdx.x ^ (15 * (h >> 4))) & 15;
  const int q0 = qb * 128;
  const int kvh = h >> 2;
  const size_t rowB = (size_t)b * 2048;
  const unsigned short* Qg = qkv + (rowB + q0) * 2560 + h * 64;
  const unsigned short* Kg = qkv + rowB * 2560 + 2048 + kvh * 64;
  const unsigned short* Vtg = vt + (size_t)(b * 8 + kvh) * 64 * 2048;
  const float SC = 0.18033688011112042f;  // (1/8)*log2(e), folded into Q

  short8 qf[2][2];
#pragma unroll
  for (int mt = 0; mt < 2; ++mt)
#pragma unroll
    for (int s = 0; s < 2; ++s) {
      int qrow = w * 32 + mt * 16 + l15;
      short8 raw = *reinterpret_cast<const short8*>(Qg + (size_t)qrow * 2560 + s * 32 + quad * 8);
      f32x4 c4 = *reinterpret_cast<const f32x4*>(fcos + (size_t)(q0 + qrow) * 32 + s * 16 + quad * 4);
      f32x4 s4 = *reinterpret_cast<const f32x4*>(fsin + (size_t)(q0 + qrow) * 32 + s * 16 + quad * 4);
      short8 o;
#pragma unroll
      for (int k = 0; k < 4; ++k) {
        float xr = bf2f((unsigned short)raw[2 * k]);
        float xi = bf2f((unsigned short)raw[2 * k + 1]);
        o[2 * k] = (short)f2bf((xr * c4[k] - xi * s4[k]) * SC);
        o[2 * k + 1] = (short)f2bf((xr * s4[k] + xi * c4[k]) * SC);
      }
      qf[mt][s] = o;
    }

  const f32x4 zf = {0.f, 0.f, 0.f, 0.f};
  f32x4 oacc[2][4];
#pragma unroll
  for (int mt = 0; mt < 2; ++mt)
#pragma unroll
    for (int nt = 0; nt < 4; ++nt) oacc[mt][nt] = zf;
  float lsum[2] = {0.f, 0.f};

  const int kb_end = 2 * qb + 2;
  const int srow = t >> 3, sc8 = t & 7;
  const int soff = srow * 64 + ((sc8 ^ (srow & 7)) * 8);
  const int asw = l15 & 7;
  short8 kreg[2], vreg[2];
#pragma unroll
  for (int r = 0; r < 2; ++r) {
    kreg[r] = *reinterpret_cast<const short8*>(Kg + (size_t)(srow + 32 * r) * 2560 + sc8 * 8);
    vreg[r] = *reinterpret_cast<const short8*>(Vtg + (size_t)(srow + 32 * r) * 2048 + sc8 * 8);
  }

  for (int kb = 0; kb < kb_end; ++kb) {
    __syncthreads();
#pragma unroll
    for (int r = 0; r < 2; ++r) {
      *reinterpret_cast<short8*>(Ks + soff + r * 32 * 64) = kreg[r];
      *reinterpret_cast<short8*>(Vs + soff + r * 32 * 64) = vreg[r];
    }
    __syncthreads();
    if (kb + 1 < kb_end) {
#pragma unroll
      for (int r = 0; r < 2; ++r) {
        kreg[r] = *reinterpret_cast<const short8*>(Kg + (size_t)((kb + 1) * 64 + srow + 32 * r) * 2560 + sc8 * 8);
        vreg[r] = *reinterpret_cast<const short8*>(Vtg + (size_t)(srow + 32 * r) * 2048 + (kb + 1) * 64 + sc8 * 8);
      }
    }
    const int qmaxw = q0 + w * 32 + 31;
    if (kb * 64 > qmaxw) continue;
    const bool needMask = (kb * 64 + 63) > (q0 + w * 32);

#pragma unroll
    for (int kvt = 0; kvt < 4; ++kvt) {
      const int pcol = ((kvt * 2 + (quad >> 1)) ^ asw) * 8 + (quad & 1) * 4;
      // kvt fully masked for this wave but inside a live PV half: zero Ps, skip compute
      if (needMask && (kb * 64 + kvt * 16 > qmaxw)) {
        if (kb * 64 + (kvt >> 1) * 32 <= qmaxw) {
#pragma unroll
          for (int qt = 0; qt < 2; ++qt)
            *reinterpret_cast<uint2*>(Ps + (size_t)(w * 32 + qt * 16 + l15) * 64 + pcol) = make_uint2(0u, 0u);
        }
        continue;
      }
      f32x4 st0 = zf, st1 = zf;
#pragma unroll
      for (int s = 0; s < 2; ++s) {
        short8 kf = *reinterpret_cast<const short8*>(Ks + (kvt * 16 + l15) * 64 + ((s * 4 + quad) ^ asw) * 8);
        st0 = __builtin_amdgcn_mfma_f32_16x16x32_bf16(kf, qf[0][s], st0, 0, 0, 0);
        st1 = __builtin_amdgcn_mfma_f32_16x16x32_bf16(kf, qf[1][s], st1, 0, 0, 0);
      }
      if (needMask) {
        const int kvb = kb * 64 + kvt * 16 + quad * 4;
#pragma unroll
        for (int qt = 0; qt < 2; ++qt) {
          const f32x4 stv = qt ? st1 : st0;
          const int qg = q0 + w * 32 + qt * 16 + l15;
          float p[4];
#pragma unroll
          for (int r = 0; r < 4; ++r) {
            float pv = __builtin_amdgcn_exp2f(stv[r]);
            p[r] = (kvb + r > qg) ? 0.f : pv;
          }
          lsum[qt] += (p[0] + p[1]) + (p[2] + p[3]);
          *reinterpret_cast<uint2*>(Ps + (size_t)(w * 32 + qt * 16 + l15) * 64 + pcol) =
              make_uint2(pkbf(p[0], p[1]), pkbf(p[2], p[3]));
        }
      } else {
#pragma unroll
        for (int qt = 0; qt < 2; ++qt) {
          const f32x4 stv = qt ? st1 : st0;
          float p[4];
#pragma unroll
          for (int r = 0; r < 4; ++r) p[r] = __builtin_amdgcn_exp2f(stv[r]);
          lsum[qt] += (p[0] + p[1]) + (p[2] + p[3]);
          *reinterpret_cast<uint2*>(Ps + (size_t)(w * 32 + qt * 16 + l15) * 64 + pcol) =
              make_uint2(pkbf(p[0], p[1]), pkbf(p[2], p[3]));
        }
      }
    }

    // O += P V (skip dead halves on diagonal tiles)
#pragma unroll
    for (int s = 0; s < 2; ++s) {
      if (needMask && (kb * 64 + s * 32 > qmaxw)) continue;
      short8 vf[4];
#pragma unroll
      for (int nt = 0; nt < 4; ++nt)
        vf[nt] = *reinterpret_cast<const short8*>(Vs + (nt * 16 + l15) * 64 + ((s * 4 + quad) ^ asw) * 8);
#pragma unroll
      for (int mt = 0; mt < 2; ++mt) {
        short8 pf = *reinterpret_cast<const short8*>(Ps + (size_t)(w * 32 + mt * 16 + l15) * 64 + ((s * 4 + quad) ^ asw) * 8);
#pragma unroll
        for (int nt = 0; nt < 4; ++nt)
          oacc[mt][nt] = __builtin_amdgcn_mfma_f32_16x16x32_bf16(pf, vf[nt], oacc[mt][nt], 0, 0, 0);
      }
    }
  }

#pragma unroll
  for (int qt = 0; qt < 2; ++qt) {
    lsum[qt] += __shfl_xor(lsum[qt], 16, 64);
    lsum[qt] += __shfl_xor(lsum[qt], 32, 64);
  }
  if (quad == 0) {
    Ls[w * 32 + l15] = lsum[0];
    Ls[w * 32 + 16 + l15] = lsum[1];
  }
  float linv[2][4];
#pragma unroll
  for (int mt = 0; mt < 2; ++mt)
#pragma unroll
    for (int r = 0; r < 4; ++r) linv[mt][r] = 1.f / Ls[w * 32 + mt * 16 + quad * 4 + r];

#pragma unroll
  for (int mt = 0; mt < 2; ++mt)
#pragma unroll
    for (int nt = 0; nt < 4; ++nt)
#pragma unroll
      for (int r = 0; r < 4; ++r) {
        size_t row = rowB + (size_t)(q0 + w * 32 + mt * 16 + quad * 4 + r);
        size_t col = (size_t)h * 64 + nt * 16 + l15;
        out[row * 2048 + col] = f2bf(oacc[mt][nt][r] * linv[mt][r]);
      }
}

extern "C" void kernel_launch(void* const* d_in, const int* in_sizes, int n_in, void* d_out,
                              int out_size, void* d_ws, size_t ws_size, hipStream_t stream) {
  const float* x = (const float*)d_in[0];
  const float* fcos = (const float*)d_in[1];
  const float* fsin = (const float*)d_in[2];
  const float* wq = (const float*)d_in[3];
  const float* wk = (const float*)d_in[4];
  const float* wv = (const float*)d_in[5];
  const float* wo = (const float*)d_in[6];

  char* ws = (char*)d_ws;
  unsigned short* xb = (unsigned short*)ws;                       // 4096x2048 bf16  @0      (16 MiB)
  unsigned short* wt = (unsigned short*)(ws + 16777216ull);       // 3072x2048 bf16  @16 MiB (12 MiB)
  unsigned short* wot = (unsigned short*)(ws + 29360128ull);      // 2048x2048 bf16  @28 MiB (8 MiB)
  unsigned short* qkv = (unsigned short*)(ws + 37748736ull);      // 4096x2560 bf16  @36 MiB (20 MiB)
  unsigned short* attno = (unsigned short*)(ws + 58720256ull);    // 4096x2048 bf16  @56 MiB (16 MiB)
  unsigned short* vt = (unsigned short*)(ws + 75497472ull);       // 16x64x2048 bf16 @72 MiB (4 MiB)

  prep<<<dim3(64, 64, 5), 256, 0, stream>>>(x, wq, wk, wv, wo, xb, wt, wot);
  // QKV GEMM: Q plain, K with fused RoPE, V transposed into vt
  gemm_bt64<1><<<dim3(24, 32), 256, 0, stream>>>(xb, wt, qkv, 2048, 2560, vt, fcos, fsin);
  flash_attn<<<dim3(16, 32, 2), 256, 0, stream>>>(qkv, vt, fcos, fsin, attno);
  gemm_bt64<0><<<dim3(16, 32), 256, 0, stream>>>(attno, wot, d_out, 2048, 2048, nullptr, nullptr, nullptr);
}